// Round 1
// baseline (516.906 us; speedup 1.0000x reference)
//
#include <hip/hip_runtime.h>
#include <hip/hip_bf16.h>
#include <math.h>

#define VOCAB 100000
#define EMBED 512
#define WINDOW 10
#define PATH 17
#define EPS 1e-9f

// Single-block kernel: the whole problem is ~55 KB of reads and ~14K MACs.
// 512 threads = 8 waves. Phase 1 computes h[] into LDS, phase 2 does the
// 17 dot products (one path per wave per iteration) with shuffle reduction.
__global__ __launch_bounds__(512)
void cbow_hs_kernel(const int* __restrict__ context_idx,
                    const int* __restrict__ path_indices,
                    const int* __restrict__ code_bits,
                    const float* __restrict__ ctx_emb,
                    const float* __restrict__ node_emb,
                    float* __restrict__ out) {
    __shared__ float h_s[EMBED];
    __shared__ float loss_s;

    const int tid = threadIdx.x;

    if (tid == 0) loss_s = 0.0f;

    // ---- Phase 1: h[d] = mean over window of ctx_emb[cidx[w]][d] ----
    // tid == d (512 threads, 512 dims). Row base addresses are wave-uniform
    // (index loads scalarize); lane accesses are fully coalesced.
    {
        float acc = 0.0f;
        #pragma unroll
        for (int w = 0; w < WINDOW; ++w) {
            const int row = context_idx[w];
            acc += ctx_emb[(size_t)row * EMBED + tid];
        }
        h_s[tid] = acc * (1.0f / WINDOW);
    }
    __syncthreads();

    // ---- Phase 2: per-path dot(node_emb[pidx[p]], h) + log-loss ----
    const int wave = tid >> 6;   // 0..7
    const int lane = tid & 63;

    for (int p = wave; p < PATH; p += 8) {
        const int row = path_indices[p];
        const float* nrow = node_emb + (size_t)row * EMBED;
        float sum = 0.0f;
        #pragma unroll
        for (int j = 0; j < EMBED / 64; ++j) {
            const int d = lane + 64 * j;
            sum += nrow[d] * h_s[d];
        }
        // wave-wide butterfly reduction (64 lanes)
        #pragma unroll
        for (int off = 32; off >= 1; off >>= 1)
            sum += __shfl_xor(sum, off, 64);

        if (lane == 0) {
            const float score = 1.0f / (1.0f + expf(-sum));
            const float term = (code_bits[p] == 1)
                                   ? -logf(score + EPS)
                                   : -logf(1.0f - score + EPS);
            atomicAdd(&loss_s, term);
        }
    }
    __syncthreads();

    if (tid == 0) out[0] = loss_s;
}

extern "C" void kernel_launch(void* const* d_in, const int* in_sizes, int n_in,
                              void* d_out, int out_size, void* d_ws, size_t ws_size,
                              hipStream_t stream) {
    const int*   context_idx  = (const int*)d_in[0];
    const int*   path_indices = (const int*)d_in[1];
    const int*   code_bits    = (const int*)d_in[2];
    const float* ctx_emb      = (const float*)d_in[3];
    const float* node_emb     = (const float*)d_in[4];
    float*       out          = (float*)d_out;

    cbow_hs_kernel<<<1, 512, 0, stream>>>(context_idx, path_indices, code_bits,
                                          ctx_emb, node_emb, out);
}

// Round 2
// 513.872 us; speedup vs baseline: 1.0059x; 1.0059x over previous
//
#include <hip/hip_runtime.h>
#include <hip/hip_bf16.h>
#include <math.h>

#define VOCAB 100000
#define EMBED 512
#define WINDOW 10
#define PATH 17
#define EPS 1e-9f

// Single-block kernel; the whole problem is ~55 KB of gathered reads,
// ~14K MACs, one scalar out. Structured for ONE global-latency round:
// node-row loads (independent of h) are issued before the barrier.
__global__ __launch_bounds__(512)
void cbow_hs_kernel(const int* __restrict__ context_idx,
                    const int* __restrict__ path_indices,
                    const int* __restrict__ code_bits,
                    const float* __restrict__ ctx_emb,
                    const float* __restrict__ node_emb,
                    float* __restrict__ out) {
    __shared__ float h_s[EMBED];
    __shared__ float loss_s;

    const int tid  = threadIdx.x;
    const int wave = tid >> 6;   // 0..7
    const int lane = tid & 63;

    if (tid == 0) loss_s = 0.0f;

    // ---- Prefetch this wave's node rows into registers (independent of h).
    // Wave w handles paths w, w+8, w+16 (only wave 0 has a third path).
    const int p0 = wave;
    const int p1 = wave + 8;
    const int p2 = wave + 16;
    const bool has1 = p1 < PATH;
    const bool has2 = p2 < PATH;
    // clamp OOB path slots to a valid index (result predicated away later)
    const int r0 = path_indices[p0];
    const int r1 = path_indices[has1 ? p1 : 0];
    const int r2 = path_indices[has2 ? p2 : 0];

    float n0[8], n1[8], n2[8];
    {
        const float* a0 = node_emb + (size_t)r0 * EMBED;
        const float* a1 = node_emb + (size_t)r1 * EMBED;
        const float* a2 = node_emb + (size_t)r2 * EMBED;
        #pragma unroll
        for (int j = 0; j < 8; ++j) n0[j] = a0[lane + 64 * j];
        #pragma unroll
        for (int j = 0; j < 8; ++j) n1[j] = a1[lane + 64 * j];
        #pragma unroll
        for (int j = 0; j < 8; ++j) n2[j] = a2[lane + 64 * j];
    }

    // ---- Phase 1: h[d] = mean over window (tid == d, coalesced). These
    // loads issue behind the node loads; one latency round covers both.
    {
        float acc = 0.0f;
        #pragma unroll
        for (int w = 0; w < WINDOW; ++w) {
            const int row = context_idx[w];
            acc += ctx_emb[(size_t)row * EMBED + tid];
        }
        h_s[tid] = acc * (1.0f / WINDOW);
    }
    __syncthreads();

    // ---- Phase 2: three dot products per wave from registers + LDS h.
    float s0 = 0.0f, s1 = 0.0f, s2 = 0.0f;
    #pragma unroll
    for (int j = 0; j < 8; ++j) {
        const float h = h_s[lane + 64 * j];   // 2 lanes/bank: conflict-free
        s0 += n0[j] * h;
        s1 += n1[j] * h;
        s2 += n2[j] * h;
    }
    // one butterfly for all three sums
    #pragma unroll
    for (int off = 32; off >= 1; off >>= 1) {
        s0 += __shfl_xor(s0, off, 64);
        s1 += __shfl_xor(s1, off, 64);
        s2 += __shfl_xor(s2, off, 64);
    }

    if (lane == 0) {
        float local = 0.0f;
        {
            const float score = 1.0f / (1.0f + expf(-s0));
            local += (code_bits[p0] == 1) ? -logf(score + EPS)
                                          : -logf(1.0f - score + EPS);
        }
        if (has1) {
            const float score = 1.0f / (1.0f + expf(-s1));
            local += (code_bits[p1] == 1) ? -logf(score + EPS)
                                          : -logf(1.0f - score + EPS);
        }
        if (has2) {
            const float score = 1.0f / (1.0f + expf(-s2));
            local += (code_bits[p2] == 1) ? -logf(score + EPS)
                                          : -logf(1.0f - score + EPS);
        }
        atomicAdd(&loss_s, local);
    }
    __syncthreads();

    if (tid == 0) out[0] = loss_s;
}

extern "C" void kernel_launch(void* const* d_in, const int* in_sizes, int n_in,
                              void* d_out, int out_size, void* d_ws, size_t ws_size,
                              hipStream_t stream) {
    const int*   context_idx  = (const int*)d_in[0];
    const int*   path_indices = (const int*)d_in[1];
    const int*   code_bits    = (const int*)d_in[2];
    const float* ctx_emb      = (const float*)d_in[3];
    const float* node_emb     = (const float*)d_in[4];
    float*       out          = (float*)d_out;

    cbow_hs_kernel<<<1, 512, 0, stream>>>(context_idx, path_indices, code_bits,
                                          ctx_emb, node_emb, out);
}